// Round 5
// baseline (5423.257 us; speedup 1.0000x reference)
//
#include <hip/hip_runtime.h>
#include <math.h>

#define B_ 64
#define T_ 512
#define H_ 1024
#define V_ 256
#define O_ 1024
#define KFC 2048

typedef short bf16x8 __attribute__((ext_vector_type(8)));
typedef _Float16 f16x8 __attribute__((ext_vector_type(8)));
typedef _Float16 f16x4 __attribute__((ext_vector_type(4)));
typedef float f32x4 __attribute__((ext_vector_type(4)));
typedef int   i32x4 __attribute__((ext_vector_type(4)));
typedef unsigned long long u64x2 __attribute__((ext_vector_type(2)));

// ---- workspace layout (bytes) ----
#define OFF_TABLE_F 0                 // [V][H] f32 (W_ih^T + b_ih + b_hh), fwd
#define OFF_TABLE_B 1048576           // same, bwd
#define OFF_XT      2097152           // [T][B] i32 (transposed x)
#define OFF_WHH     2228224           // fp16 [d][cs][kt][ct][lane][8] (4 MB)
#define OFF_WFC     6422528           // bf16 [ob][k32][nt][lane][8] (4 MB)
#define OFF_HSF     10616832          // [T][B][H] bf16 (64 MB)
#define OFF_HSB     77725696          // [T][B][H] bf16 (64 MB)
#define OFF_XCH     144834560         // fp16 [d][par][b:64][k:1024] (512 KB)
#define OFF_CNT     145358848         // flags [d][bg][bt][cs*2+ct] u32 (8 KB reserved)

__device__ __forceinline__ unsigned short f2bf(float f) {
  union { float f; unsigned int u; } un; un.f = f;
  unsigned int u = un.u;
  unsigned int r = u + 0x7FFFu + ((u >> 16) & 1u);
  return (unsigned short)(r >> 16);
}

// ---------------- prep: tables, transposes, fragment-packed weights ----------------
__global__ void prep_kernel(const int* __restrict__ x,
    const float* __restrict__ WihF, const float* __restrict__ WhhF,
    const float* __restrict__ bihF, const float* __restrict__ bhhF,
    const float* __restrict__ WihB, const float* __restrict__ WhhB,
    const float* __restrict__ bihB, const float* __restrict__ bhhB,
    const float* __restrict__ Wfc,
    float* __restrict__ tableF, float* __restrict__ tableB,
    int* __restrict__ xT, short* __restrict__ whhpack,
    short* __restrict__ wfcpack, unsigned int* __restrict__ cnt)
{
  const long NT1 = 524288, NT2 = 32768, NT3 = 2097152, NT4 = 2097152, NT5 = 2048;
  const long total = NT1 + NT2 + NT3 + NT4 + NT5;
  for (long i = (long)blockIdx.x * blockDim.x + threadIdx.x; i < total;
       i += (long)gridDim.x * blockDim.x) {
    long j = i;
    if (j < NT1) {
      int d = (int)(j >> 18);
      int r = (int)(j & 262143);
      int v = r >> 10, h = r & 1023;
      const float* Wih = d ? WihB : WihF;
      const float* bi  = d ? bihB : bihF;
      const float* bh  = d ? bhhB : bhhF;
      (d ? tableB : tableF)[r] = Wih[h * V_ + v] + bi[h] + bh[h];
      continue;
    }
    j -= NT1;
    if (j < NT2) {
      int t = (int)(j >> 6), bb = (int)(j & 63);
      xT[j] = x[bb * T_ + t];
      continue;
    }
    j -= NT2;
    if (j < NT3) {
      int d = (int)(j >> 20);
      int r = (int)(j & 1048575);
      int jj = r & 7;
      int lanei = (r >> 3) & 63;
      int cti = (r >> 9) & 1;
      int kt = (r >> 10) & 31;
      int csi = r >> 15;
      int c = csi * 32 + cti * 16 + (lanei & 15);       // A-operand m-index = col
      int k = kt * 32 + (lanei >> 4) * 8 + jj;          // same k-bijection as B
      float w = (d ? WhhB : WhhF)[c * H_ + k];
      _Float16 wh = (_Float16)w;
      whhpack[((long)d << 20) + r] = __builtin_bit_cast(short, wh);
      continue;
    }
    j -= NT3;
    if (j < NT4) {
      int jj = (int)(j & 7);
      int lanei = (int)((j >> 3) & 63);
      int nti = (int)((j >> 9) & 3);
      int k32 = (int)((j >> 11) & 63);
      int obi = (int)(j >> 17);
      int o = obi * 64 + nti * 16 + (lanei & 15);
      int k = k32 * 32 + (lanei >> 4) * 8 + jj;
      wfcpack[j] = (short)f2bf(Wfc[(long)o * KFC + k]);
      continue;
    }
    j -= NT4;
    cnt[j] = 0;
  }
}

// ---------------- persistent bidirectional recurrence (barrier-free steps) --------
// 128 WGs x 256 thr; wave = (dir, bg, cs, ct, bt). Dependency group = (dir,bg,bt):
// 64 waves exchanging h[16 rows][1024 cols]. Swapped MFMA operands:
//   D[c][b] = sum_k W[c][k] * h[b][k]; A = W (m=c), B = h (n=b).
// Producer thread holds 4 contiguous cols of one row -> 1 u64 direct publish.
// Consumer lane loads 16B contiguous k -> B-frag directly, no LDS staging.
__global__ __launch_bounds__(256, 1)
void rnn_kernel(const int* __restrict__ xT,
                const float* __restrict__ tableF, const float* __restrict__ tableB,
                const short* __restrict__ whhpack,
                short* __restrict__ hsF, short* __restrict__ hsB,
                short* __restrict__ xch, unsigned int* __restrict__ cnt)
{
  extern __shared__ char lds[];   // 64 KB: W A-frags, fragment-linear
  const int tid = threadIdx.x;
  const int wg = blockIdx.x;
  const int dir = wg >> 6;
  const int bg = (wg >> 5) & 1;
  const int cs = wg & 31;
  const int lane = tid & 63;
  const int wv = tid >> 6;
  const int ct = wv & 1;       // 16-col tile within this WG's 32-col slice
  const int bt = wv >> 1;      // 16-row tile within this WG's 32-row group
  const float* table = dir ? tableB : tableF;
  short* hs = dir ? hsB : hsF;

  // one-time: W slice -> LDS (A-operand fragments)
  {
    const i32x4* wsrc = (const i32x4*)whhpack + (size_t)(dir * 32 + cs) * 4096;
    i32x4* wdst = (i32x4*)lds;
    #pragma unroll
    for (int it = 0; it < 16; ++it)
      wdst[it * 256 + tid] = wsrc[it * 256 + tid];
  }
  __syncthreads();

  const int b = bg * 32 + bt * 16 + (lane & 15);        // my batch row (in & out)
  const int c4 = cs * 32 + ct * 16 + (lane >> 4) * 4;   // my 4 output cols
  unsigned int* fb = cnt + ((dir * 2 + bg) * 2 + bt) * 64;  // group's 64 flags
  unsigned int* myflag = fb + cs * 2 + ct;
  unsigned long long* xch64 = (unsigned long long*)xch; // [d][par][b:64][k/4:256]

  for (int s = 0; s < T_; ++s) {
    const int t = dir ? (T_ - 1 - s) : s;
    const int v = xT[t * B_ + b];
    const f32x4 xwv = *(const f32x4*)(table + v * H_ + c4);

    f32x4 z = {0.f, 0.f, 0.f, 0.f};
    f32x4 acc4[4] = {z, z, z, z};

    if (s > 0) {
      // wait: all 64 producer-waves of my group published step s-1
      const unsigned int tgt = (unsigned int)s;
      while (__ballot(__hip_atomic_load(fb + lane, __ATOMIC_RELAXED,
                                        __HIP_MEMORY_SCOPE_AGENT) < tgt))
        __builtin_amdgcn_s_sleep(1);

      // direct B-frag loads: 64 u64 sc1 loads, all issued before consumption
      const unsigned long long* src =
          xch64 + (size_t)(dir * 2 + ((s - 1) & 1)) * 16384 + b * 256 +
          (lane >> 4) * 2;
      unsigned long long bl[32], bh[32];
      #pragma unroll
      for (int kt = 0; kt < 32; ++kt) {
        bl[kt] = __hip_atomic_load(src + kt * 8, __ATOMIC_RELAXED,
                                   __HIP_MEMORY_SCOPE_AGENT);
        bh[kt] = __hip_atomic_load(src + kt * 8 + 1, __ATOMIC_RELAXED,
                                   __HIP_MEMORY_SCOPE_AGENT);
      }
      #pragma unroll
      for (int kt = 0; kt < 32; ++kt) {
        u64x2 bv = {bl[kt], bh[kt]};
        f16x8 bf = __builtin_bit_cast(f16x8, bv);
        f16x8 af = *(const f16x8*)(lds + (kt * 2 + ct) * 1024 + lane * 16);
        acc4[kt & 3] =
            __builtin_amdgcn_mfma_f32_16x16x32_f16(af, bf, acc4[kt & 3], 0, 0, 0);
      }
    }
    f32x4 accs = (acc4[0] + acc4[1]) + (acc4[2] + acc4[3]);

    // epilogue: tanh; direct register publish (no LDS bounce, no barriers)
    f16x4 hv;
    unsigned long long hbits = 0;
    #pragma unroll
    for (int r = 0; r < 4; ++r) {
      float zz = accs[r] + xwv[r];
      float e = __expf(2.0f * zz);
      float h = (e - 1.0f) / (e + 1.0f);
      hv[r] = (_Float16)h;
      hbits |= ((unsigned long long)f2bf(h)) << (16 * r);
    }
    *(unsigned long long*)(hs + ((size_t)t * B_ + b) * H_ + c4) = hbits;
    if (s < T_ - 1) {
      __hip_atomic_store(
          xch64 + (size_t)(dir * 2 + (s & 1)) * 16384 + b * 256 + (c4 >> 2),
          __builtin_bit_cast(unsigned long long, hv),
          __ATOMIC_RELAXED, __HIP_MEMORY_SCOPE_AGENT);
      asm volatile("s_waitcnt vmcnt(0)" ::: "memory");  // data acked at L3
      if (lane == 0)
        __hip_atomic_store(myflag, (unsigned int)(s + 1), __ATOMIC_RELAXED,
                           __HIP_MEMORY_SCOPE_AGENT);
    }
  }
}

// ---------------- FC: out[B*T,1024] = concat(hf,hb) @ Wfc^T + b ----------------
__global__ __launch_bounds__(256, 4)
void fc_kernel(const short* __restrict__ hsF, const short* __restrict__ hsB,
               const short* __restrict__ wfcpack, const float* __restrict__ bfc,
               float* __restrict__ out)
{
  __shared__ short Alds[64 * 64];          // [row][k] swizzled
  __shared__ short Blds[2 * 4 * 64 * 8];   // fragment-linear
  const int tid = threadIdx.x;
  const int lane = tid & 63;
  const int wv = tid >> 6;
  const int mt2 = wv & 1;
  const int nt2 = wv >> 1;
  const int r0 = blockIdx.x * 64;
  const int ob = blockIdx.y;
  const int bb = r0 >> 9;
  const int t0 = r0 & 511;

  f32x4 z = {0.f, 0.f, 0.f, 0.f};
  f32x4 acc[2][2] = {{z, z}, {z, z}};

  for (int kc = 0; kc < KFC / 64; ++kc) {
    {  // stage A tile (64 rows x 64 k)
      int row = tid >> 2;
      int kq = (tid & 3) * 16;
      int k0 = kc * 64;
      const short* hsrc = (k0 < H_) ? hsF : hsB;
      int kk = (k0 < H_) ? k0 : (k0 - H_);
      const short* src = hsrc + ((size_t)(t0 + row) * B_ + bb) * H_ + kk + kq;
      i32x4 v0 = *(const i32x4*)(src);
      i32x4 v1 = *(const i32x4*)(src + 8);
      int sw = (row & 7) << 4;
      *(i32x4*)((char*)Alds + row * 128 + ((kq * 2) ^ sw)) = v0;
      *(i32x4*)((char*)Alds + row * 128 + ((kq * 2 + 16) ^ sw)) = v1;
    }
    {  // stage B tile (fragment-linear, contiguous copy)
      const i32x4* src = (const i32x4*)(wfcpack + ((size_t)ob * 64 + kc * 2) * 2048);
      i32x4* dst = (i32x4*)Blds;
      dst[tid] = src[tid];
      dst[tid + 256] = src[tid + 256];
    }
    __syncthreads();
    #pragma unroll
    for (int k2 = 0; k2 < 2; ++k2) {
      bf16x8 afr[2];
      #pragma unroll
      for (int mi = 0; mi < 2; ++mi) {
        int row = mt2 * 32 + mi * 16 + (lane & 15);
        int off = (k2 * 64 + (lane >> 4) * 16) ^ ((row & 7) << 4);
        afr[mi] = *(const bf16x8*)((const char*)Alds + row * 128 + off);
      }
      #pragma unroll
      for (int ni = 0; ni < 2; ++ni) {
        int ntg = nt2 * 2 + ni;
        bf16x8 bfr = *(const bf16x8*)((const char*)Blds + ((k2 * 4 + ntg) * 64 + lane) * 16);
        #pragma unroll
        for (int mi = 0; mi < 2; ++mi)
          acc[mi][ni] = __builtin_amdgcn_mfma_f32_16x16x32_bf16(afr[mi], bfr, acc[mi][ni], 0, 0, 0);
      }
    }
    __syncthreads();
  }
  #pragma unroll
  for (int mi = 0; mi < 2; ++mi) {
    int row = r0 + mt2 * 32 + mi * 16 + (lane >> 4) * 4;
    #pragma unroll
    for (int ni = 0; ni < 2; ++ni) {
      int o = ob * 64 + nt2 * 32 + ni * 16 + (lane & 15);
      float bias = bfc[o];
      #pragma unroll
      for (int r = 0; r < 4; ++r)
        out[(size_t)(row + r) * O_ + o] = acc[mi][ni][r] + bias;
    }
  }
}

extern "C" void kernel_launch(void* const* d_in, const int* in_sizes, int n_in,
                              void* d_out, int out_size, void* d_ws, size_t ws_size,
                              hipStream_t stream) {
  const int* x = (const int*)d_in[0];
  const float* WihF = (const float*)d_in[1];
  const float* WhhF = (const float*)d_in[2];
  const float* bihF = (const float*)d_in[3];
  const float* bhhF = (const float*)d_in[4];
  const float* WihB = (const float*)d_in[5];
  const float* WhhB = (const float*)d_in[6];
  const float* bihB = (const float*)d_in[7];
  const float* bhhB = (const float*)d_in[8];
  const float* Wfc  = (const float*)d_in[9];
  const float* bfc  = (const float*)d_in[10];
  float* out = (float*)d_out;
  char* ws = (char*)d_ws;

  float* tableF = (float*)(ws + OFF_TABLE_F);
  float* tableB = (float*)(ws + OFF_TABLE_B);
  int* xT = (int*)(ws + OFF_XT);
  short* whhpack = (short*)(ws + OFF_WHH);
  short* wfcpack = (short*)(ws + OFF_WFC);
  short* hsF = (short*)(ws + OFF_HSF);
  short* hsB = (short*)(ws + OFF_HSB);
  short* xch = (short*)(ws + OFF_XCH);
  unsigned int* cnt = (unsigned int*)(ws + OFF_CNT);

  hipFuncSetAttribute((const void*)rnn_kernel,
                      hipFuncAttributeMaxDynamicSharedMemorySize, 65536);

  prep_kernel<<<dim3(2048), dim3(256), 0, stream>>>(
      x, WihF, WhhF, bihF, bhhF, WihB, WhhB, bihB, bhhB, Wfc,
      tableF, tableB, xT, whhpack, wfcpack, cnt);
  rnn_kernel<<<dim3(128), dim3(256), 65536, stream>>>(
      xT, tableF, tableB, whhpack, hsF, hsB, xch, cnt);
  fc_kernel<<<dim3(512, 16), dim3(256), 0, stream>>>(
      hsF, hsB, wfcpack, bfc, out);
}

// Round 6
// 4840.706 us; speedup vs baseline: 1.1203x; 1.1203x over previous
//
#include <hip/hip_runtime.h>
#include <math.h>

#define B_ 64
#define T_ 512
#define H_ 1024
#define V_ 256
#define O_ 1024
#define KFC 2048

typedef short bf16x8 __attribute__((ext_vector_type(8)));
typedef _Float16 f16x8 __attribute__((ext_vector_type(8)));
typedef float f32x4 __attribute__((ext_vector_type(4)));
typedef int   i32x4 __attribute__((ext_vector_type(4)));
typedef unsigned long long u64x2 __attribute__((ext_vector_type(2)));

// ---- workspace layout (bytes) ----
#define OFF_TABLE_F 0                 // [V][H] f32 (W_ih^T + b_ih + b_hh), fwd
#define OFF_TABLE_B 1048576           // same, bwd
#define OFF_XT      2097152           // [T][B] i32 (transposed x)
#define OFF_WHH     2228224           // fp16 [d][cs64][kt32][lane64][8] (4 MB)
#define OFF_WFC     6422528           // bf16 [ob][k32][nt][lane][8] (4 MB)
#define OFF_HSF     10616832          // [T][B][H] bf16 (64 MB)
#define OFF_HSB     77725696          // [T][B][H] bf16 (64 MB)
#define OFF_XCH     144834560         // u64 [d][par][bt4][kt32][q2][lane64] (512 KB)
#define OFF_CNT     145358848         // flags [d][cs64][bt4] u32 (8 KB reserved)

__device__ __forceinline__ unsigned short f2bf(float f) {
  union { float f; unsigned int u; } un; un.f = f;
  unsigned int u = un.u;
  unsigned int r = u + 0x7FFFu + ((u >> 16) & 1u);
  return (unsigned short)(r >> 16);
}

// ---------------- prep: tables, transposes, fragment-packed weights ----------------
__global__ void prep_kernel(const int* __restrict__ x,
    const float* __restrict__ WihF, const float* __restrict__ WhhF,
    const float* __restrict__ bihF, const float* __restrict__ bhhF,
    const float* __restrict__ WihB, const float* __restrict__ WhhB,
    const float* __restrict__ bihB, const float* __restrict__ bhhB,
    const float* __restrict__ Wfc,
    float* __restrict__ tableF, float* __restrict__ tableB,
    int* __restrict__ xT, short* __restrict__ whhpack,
    short* __restrict__ wfcpack, unsigned int* __restrict__ cnt)
{
  const long NT1 = 524288, NT2 = 32768, NT3 = 2097152, NT4 = 2097152, NT5 = 2048;
  const long total = NT1 + NT2 + NT3 + NT4 + NT5;
  for (long i = (long)blockIdx.x * blockDim.x + threadIdx.x; i < total;
       i += (long)gridDim.x * blockDim.x) {
    long j = i;
    if (j < NT1) {
      int d = (int)(j >> 18);
      int r = (int)(j & 262143);
      int v = r >> 10, h = r & 1023;
      const float* Wih = d ? WihB : WihF;
      const float* bi  = d ? bihB : bihF;
      const float* bh  = d ? bhhB : bhhF;
      (d ? tableB : tableF)[r] = Wih[h * V_ + v] + bi[h] + bh[h];
      continue;
    }
    j -= NT1;
    if (j < NT2) {
      int t = (int)(j >> 6), bb = (int)(j & 63);
      xT[j] = x[bb * T_ + t];
      continue;
    }
    j -= NT2;
    if (j < NT3) {
      // whhpack [d][cs64][kt32][lane64][8]: c = cs*16 + (lane&15),
      // k = kt*32 + (lane>>4)*8 + jj  (same k-bijection as B-frags)
      int d = (int)(j >> 20);
      int r = (int)(j & 1048575);
      int jj = r & 7;
      int lanei = (r >> 3) & 63;
      int kt = (r >> 9) & 31;
      int csi = (r >> 14) & 63;
      int c = csi * 16 + (lanei & 15);
      int k = kt * 32 + (lanei >> 4) * 8 + jj;
      float w = (d ? WhhB : WhhF)[c * H_ + k];
      _Float16 wh = (_Float16)w;
      whhpack[j] = __builtin_bit_cast(short, wh);
      continue;
    }
    j -= NT3;
    if (j < NT4) {
      int jj = (int)(j & 7);
      int lanei = (int)((j >> 3) & 63);
      int nti = (int)((j >> 9) & 3);
      int k32 = (int)((j >> 11) & 63);
      int obi = (int)(j >> 17);
      int o = obi * 64 + nti * 16 + (lanei & 15);
      int k = k32 * 32 + (lanei >> 4) * 8 + jj;
      wfcpack[j] = (short)f2bf(Wfc[(long)o * KFC + k]);
      continue;
    }
    j -= NT4;
    cnt[j] = 0;
  }
}

// ---------------- persistent bidirectional recurrence ----------------
// 64 WGs x 256 thr. WG = cs (16-col slice); wave = bt (16-row tile).
// Each wave runs BOTH dirs as 2 interleaved chains through one staging bank R.
// Dependency class (dir,bt): 64 producer-waves <-> 64 consumer-waves.
// Zero barriers in the step loop; coalesced fragment-linear exchange.
__global__ __launch_bounds__(256, 1)
void rnn_kernel(const int* __restrict__ xT,
                const float* __restrict__ tableF, const float* __restrict__ tableB,
                const short* __restrict__ whhpack,
                short* __restrict__ hsF, short* __restrict__ hsB,
                short* __restrict__ xch, unsigned int* __restrict__ cnt)
{
  extern __shared__ char lds[];   // 64 KB: W frags, [d][kt][lane][16B]
  const int tid = threadIdx.x;
  const int cs = blockIdx.x;       // 0..63
  const int lane = tid & 63;
  const int bt = tid >> 6;         // 0..3
  const int row = bt * 16 + (lane & 15);           // my batch row
  const int c4base = cs * 16 + ((lane >> 4) * 4);  // my 4 output cols
  unsigned long long* xch64 = (unsigned long long*)xch;
  // producer slot: [bt][kt=c4>>5][q=(c4>>2)&1][lane' = (lane&15)+16*((c4>>3)&3)]
  const int pub_off = bt * 4096 + (c4base >> 5) * 128 +
                      (((c4base >> 2) & 1) * 64) +
                      (lane & 15) + (((c4base >> 3) & 3) * 16);

  // one-time: W slice (both dirs) -> LDS, fragment-linear
  {
    const i32x4* wsrc = (const i32x4*)whhpack;
    i32x4* wdst = (i32x4*)lds;
    #pragma unroll
    for (int it = 0; it < 16; ++it) {
      int idx = it * 256 + tid;          // 0..4095 16B-units
      int d = idx >> 11, rem = idx & 2047;
      wdst[idx] = wsrc[(size_t)(d * 64 + cs) * 2048 + rem];
    }
  }
  __syncthreads();

  unsigned long long R[64];
  f32x4 zv = {0.f, 0.f, 0.f, 0.f};
  f32x4 acc4[4];

#define POLLW(d, tgt) do { \
    const unsigned int* fp = cnt + ((d) * 64 + lane) * 4 + bt; \
    while (__ballot(__hip_atomic_load(fp, __ATOMIC_RELAXED, \
                                      __HIP_MEMORY_SCOPE_AGENT) < (unsigned)(tgt))) {} \
    __asm__ __volatile__("" ::: "memory"); \
  } while (0)

#define LOADR(d, par) do { \
    const unsigned long long* sp = xch64 + \
        (size_t)(((d) * 2 + (par)) * 16384 + bt * 4096 + lane); \
    _Pragma("unroll") \
    for (int kt = 0; kt < 32; ++kt) { \
      R[2 * kt]     = __hip_atomic_load(sp + kt * 128,      __ATOMIC_RELAXED, \
                                        __HIP_MEMORY_SCOPE_AGENT); \
      R[2 * kt + 1] = __hip_atomic_load(sp + kt * 128 + 64, __ATOMIC_RELAXED, \
                                        __HIP_MEMORY_SCOPE_AGENT); \
    } \
  } while (0)

#define MFMA_PHASE(d) do { \
    acc4[0] = zv; acc4[1] = zv; acc4[2] = zv; acc4[3] = zv; \
    _Pragma("unroll") \
    for (int kt = 0; kt < 32; ++kt) { \
      f16x8 af = *(const f16x8*)(lds + (((d) * 32 + kt) * 64 + lane) * 16); \
      u64x2 bv; bv[0] = R[2 * kt]; bv[1] = R[2 * kt + 1]; \
      f16x8 bf = __builtin_bit_cast(f16x8, bv); \
      acc4[kt & 3] = __builtin_amdgcn_mfma_f32_16x16x32_f16(af, bf, acc4[kt & 3], 0, 0, 0); \
    } \
  } while (0)

#define PUBLISH(d, par, tval, xwv, hsp) do { \
    f32x4 accs = (acc4[0] + acc4[1]) + (acc4[2] + acc4[3]); \
    unsigned long long hb = 0, hx = 0; \
    _Pragma("unroll") \
    for (int r = 0; r < 4; ++r) { \
      float z2 = accs[r] + (xwv)[r]; \
      float e = __expf(2.0f * z2); \
      float h = (e - 1.0f) / (e + 1.0f); \
      hb |= ((unsigned long long)f2bf(h)) << (16 * r); \
      union { _Float16 f; unsigned short u; } cv; cv.f = (_Float16)h; \
      hx |= ((unsigned long long)cv.u) << (16 * r); \
    } \
    *(unsigned long long*)((hsp) + ((size_t)(tval) * 64 + row) * 1024 + c4base) = hb; \
    __hip_atomic_store(xch64 + (size_t)(((d) * 2 + (par)) * 16384) + pub_off, hx, \
                       __ATOMIC_RELAXED, __HIP_MEMORY_SCOPE_AGENT); \
  } while (0)

#define SETFLAG(d, val) do { \
    if (lane == 0) \
      __hip_atomic_store(cnt + ((d) * 64 + cs) * 4 + bt, (unsigned)(val), \
                         __ATOMIC_RELAXED, __HIP_MEMORY_SCOPE_AGENT); \
  } while (0)

  // ---- prologue: step 0 both dirs (h_0 = tanh(xw), no recurrent term) ----
  {
    acc4[0] = zv; acc4[1] = zv; acc4[2] = zv; acc4[3] = zv;
    int v0 = xT[0 * 64 + row];
    f32x4 xw0 = *(const f32x4*)(tableF + v0 * 1024 + c4base);
    PUBLISH(0, 0, 0, xw0, hsF);
    int v1 = xT[511 * 64 + row];
    f32x4 xw1 = *(const f32x4*)(tableB + v1 * 1024 + c4base);
    PUBLISH(1, 0, 511, xw1, hsB);
    __asm__ __volatile__("s_waitcnt vmcnt(0)" ::: "memory");
    SETFLAG(0, 1);
    SETFLAG(1, 1);
  }
  POLLW(0, 1);
  LOADR(0, 0);

  for (int s = 1; s < 512; ++s) {
    const int pp = (s - 1) & 1, pc = s & 1;
    // ---- C0: dir0 step s (consume R = d0 h_{s-1}) ----
    int va = xT[s * 64 + row];
    f32x4 xwa = *(const f32x4*)(tableF + va * 1024 + c4base);
    MFMA_PHASE(0);
    PUBLISH(0, pc, s, xwa, hsF);
    // ---- I1: poll dir1 step s-1 published ----
    POLLW(1, s);
    __asm__ __volatile__("s_waitcnt vmcnt(0)" ::: "memory");
    SETFLAG(0, s + 1);
    LOADR(1, pp);        // d1 h_{s-1}; RT hides under next poll
    // ---- I0: poll dir0 step s published (by everyone) ----
    POLLW(0, s + 1);
    // ---- C1: dir1 step s ----
    int t1 = 511 - s;
    int vb = xT[t1 * 64 + row];
    f32x4 xwb = *(const f32x4*)(tableB + vb * 1024 + c4base);
    MFMA_PHASE(1);
    LOADR(0, pc);        // prefetch d0 h_s for next iteration
    PUBLISH(1, pc, t1, xwb, hsB);
    __asm__ __volatile__("s_waitcnt vmcnt(0)" ::: "memory");
    SETFLAG(1, s + 1);
  }
#undef POLLW
#undef LOADR
#undef MFMA_PHASE
#undef PUBLISH
#undef SETFLAG
}

// ---------------- FC: out[B*T,1024] = concat(hf,hb) @ Wfc^T + b ----------------
__global__ __launch_bounds__(256, 4)
void fc_kernel(const short* __restrict__ hsF, const short* __restrict__ hsB,
               const short* __restrict__ wfcpack, const float* __restrict__ bfc,
               float* __restrict__ out)
{
  __shared__ short Alds[64 * 64];          // [row][k] swizzled
  __shared__ short Blds[2 * 4 * 64 * 8];   // fragment-linear
  const int tid = threadIdx.x;
  const int lane = tid & 63;
  const int wv = tid >> 6;
  const int mt2 = wv & 1;
  const int nt2 = wv >> 1;
  const int r0 = blockIdx.x * 64;
  const int ob = blockIdx.y;
  const int bb = r0 >> 9;
  const int t0 = r0 & 511;

  f32x4 z = {0.f, 0.f, 0.f, 0.f};
  f32x4 acc[2][2] = {{z, z}, {z, z}};

  for (int kc = 0; kc < KFC / 64; ++kc) {
    {  // stage A tile (64 rows x 64 k)
      int row = tid >> 2;
      int kq = (tid & 3) * 16;
      int k0 = kc * 64;
      const short* hsrc = (k0 < H_) ? hsF : hsB;
      int kk = (k0 < H_) ? k0 : (k0 - H_);
      const short* src = hsrc + ((size_t)(t0 + row) * B_ + bb) * H_ + kk + kq;
      i32x4 v0 = *(const i32x4*)(src);
      i32x4 v1 = *(const i32x4*)(src + 8);
      int sw = (row & 7) << 4;
      *(i32x4*)((char*)Alds + row * 128 + ((kq * 2) ^ sw)) = v0;
      *(i32x4*)((char*)Alds + row * 128 + ((kq * 2 + 16) ^ sw)) = v1;
    }
    {  // stage B tile (fragment-linear, contiguous copy)
      const i32x4* src = (const i32x4*)(wfcpack + ((size_t)ob * 64 + kc * 2) * 2048);
      i32x4* dst = (i32x4*)Blds;
      dst[tid] = src[tid];
      dst[tid + 256] = src[tid + 256];
    }
    __syncthreads();
    #pragma unroll
    for (int k2 = 0; k2 < 2; ++k2) {
      bf16x8 afr[2];
      #pragma unroll
      for (int mi = 0; mi < 2; ++mi) {
        int row = mt2 * 32 + mi * 16 + (lane & 15);
        int off = (k2 * 64 + (lane >> 4) * 16) ^ ((row & 7) << 4);
        afr[mi] = *(const bf16x8*)((const char*)Alds + row * 128 + off);
      }
      #pragma unroll
      for (int ni = 0; ni < 2; ++ni) {
        int ntg = nt2 * 2 + ni;
        bf16x8 bfr = *(const bf16x8*)((const char*)Blds + ((k2 * 4 + ntg) * 64 + lane) * 16);
        #pragma unroll
        for (int mi = 0; mi < 2; ++mi)
          acc[mi][ni] = __builtin_amdgcn_mfma_f32_16x16x32_bf16(afr[mi], bfr, acc[mi][ni], 0, 0, 0);
      }
    }
    __syncthreads();
  }
  #pragma unroll
  for (int mi = 0; mi < 2; ++mi) {
    int row = r0 + mt2 * 32 + mi * 16 + (lane >> 4) * 4;
    #pragma unroll
    for (int ni = 0; ni < 2; ++ni) {
      int o = ob * 64 + nt2 * 32 + ni * 16 + (lane & 15);
      float bias = bfc[o];
      #pragma unroll
      for (int r = 0; r < 4; ++r)
        out[(size_t)(row + r) * O_ + o] = acc[mi][ni][r] + bias;
    }
  }
}

extern "C" void kernel_launch(void* const* d_in, const int* in_sizes, int n_in,
                              void* d_out, int out_size, void* d_ws, size_t ws_size,
                              hipStream_t stream) {
  const int* x = (const int*)d_in[0];
  const float* WihF = (const float*)d_in[1];
  const float* WhhF = (const float*)d_in[2];
  const float* bihF = (const float*)d_in[3];
  const float* bhhF = (const float*)d_in[4];
  const float* WihB = (const float*)d_in[5];
  const float* WhhB = (const float*)d_in[6];
  const float* bihB = (const float*)d_in[7];
  const float* bhhB = (const float*)d_in[8];
  const float* Wfc  = (const float*)d_in[9];
  const float* bfc  = (const float*)d_in[10];
  float* out = (float*)d_out;
  char* ws = (char*)d_ws;

  float* tableF = (float*)(ws + OFF_TABLE_F);
  float* tableB = (float*)(ws + OFF_TABLE_B);
  int* xT = (int*)(ws + OFF_XT);
  short* whhpack = (short*)(ws + OFF_WHH);
  short* wfcpack = (short*)(ws + OFF_WFC);
  short* hsF = (short*)(ws + OFF_HSF);
  short* hsB = (short*)(ws + OFF_HSB);
  short* xch = (short*)(ws + OFF_XCH);
  unsigned int* cnt = (unsigned int*)(ws + OFF_CNT);

  hipFuncSetAttribute((const void*)rnn_kernel,
                      hipFuncAttributeMaxDynamicSharedMemorySize, 65536);

  prep_kernel<<<dim3(2048), dim3(256), 0, stream>>>(
      x, WihF, WhhF, bihF, bhhF, WihB, WhhB, bihB, bhhB, Wfc,
      tableF, tableB, xT, whhpack, wfcpack, cnt);
  rnn_kernel<<<dim3(64), dim3(256), 65536, stream>>>(
      xT, tableF, tableB, whhpack, hsF, hsB, xch, cnt);
  fc_kernel<<<dim3(512, 16), dim3(256), 0, stream>>>(
      hsF, hsB, wfcpack, bfc, out);
}

// Round 7
// 1996.824 us; speedup vs baseline: 2.7159x; 2.4242x over previous
//
#include <hip/hip_runtime.h>
#include <math.h>

#define B_ 64
#define T_ 512
#define H_ 1024
#define V_ 256
#define O_ 1024
#define KFC 2048

typedef short bf16x8 __attribute__((ext_vector_type(8)));
typedef _Float16 f16x8 __attribute__((ext_vector_type(8)));
typedef float f32x4 __attribute__((ext_vector_type(4)));
typedef int   i32x4 __attribute__((ext_vector_type(4)));
typedef unsigned long long u64x2 __attribute__((ext_vector_type(2)));

// ---- workspace layout (bytes) ----
#define OFF_TABLE_F 0                 // [V][H] f32 (W_ih^T + b_ih + b_hh), fwd
#define OFF_TABLE_B 1048576           // same, bwd
#define OFF_XT      2097152           // [T][B] i32 (transposed x)
#define OFF_WHH     2228224           // fp16 [d][cs16][ct4][kt32][lane64][8] (4 MB)
#define OFF_WFC     6422528           // bf16 [ob][k32][nt][lane][8] (4 MB)
#define OFF_HSF     10616832          // [T][B][H] bf16 (64 MB)
#define OFF_HSB     77725696          // [T][B][H] bf16 (64 MB)
#define OFF_XCH     144834560         // u64 [d][par][bt4][kt32][q2][lane64] (512 KB)
#define OFF_CNT     145358848         // flags [d][bt4][cs*4+ct] u32 (8 KB reserved)

__device__ __forceinline__ unsigned short f2bf(float f) {
  union { float f; unsigned int u; } un; un.f = f;
  unsigned int u = un.u;
  unsigned int r = u + 0x7FFFu + ((u >> 16) & 1u);
  return (unsigned short)(r >> 16);
}

// ---------------- prep: tables, transposes, fragment-packed weights ----------------
__global__ void prep_kernel(const int* __restrict__ x,
    const float* __restrict__ WihF, const float* __restrict__ WhhF,
    const float* __restrict__ bihF, const float* __restrict__ bhhF,
    const float* __restrict__ WihB, const float* __restrict__ WhhB,
    const float* __restrict__ bihB, const float* __restrict__ bhhB,
    const float* __restrict__ Wfc,
    float* __restrict__ tableF, float* __restrict__ tableB,
    int* __restrict__ xT, short* __restrict__ whhpack,
    short* __restrict__ wfcpack, unsigned int* __restrict__ cnt)
{
  const long NT1 = 524288, NT2 = 32768, NT3 = 2097152, NT4 = 2097152, NT5 = 2048;
  const long total = NT1 + NT2 + NT3 + NT4 + NT5;
  for (long i = (long)blockIdx.x * blockDim.x + threadIdx.x; i < total;
       i += (long)gridDim.x * blockDim.x) {
    long j = i;
    if (j < NT1) {
      int d = (int)(j >> 18);
      int r = (int)(j & 262143);
      int v = r >> 10, h = r & 1023;
      const float* Wih = d ? WihB : WihF;
      const float* bi  = d ? bihB : bihF;
      const float* bh  = d ? bhhB : bhhF;
      (d ? tableB : tableF)[r] = Wih[h * V_ + v] + bi[h] + bh[h];
      continue;
    }
    j -= NT1;
    if (j < NT2) {
      int t = (int)(j >> 6), bb = (int)(j & 63);
      xT[j] = x[bb * T_ + t];
      continue;
    }
    j -= NT2;
    if (j < NT3) {
      // whhpack [d][cs16][ct4][kt32][lane64][8]:
      //   c = cs*64 + ct*16 + (lane&15), k = kt*32 + (lane>>4)*8 + jj
      int d = (int)(j >> 20);
      int r = (int)(j & 1048575);
      int jj = r & 7;
      int lanei = (r >> 3) & 63;
      int kt = (r >> 9) & 31;
      int cti = (r >> 14) & 3;
      int csi = (r >> 16) & 15;
      int c = csi * 64 + cti * 16 + (lanei & 15);
      int k = kt * 32 + (lanei >> 4) * 8 + jj;
      float w = (d ? WhhB : WhhF)[c * H_ + k];
      _Float16 wh = (_Float16)w;
      whhpack[j] = __builtin_bit_cast(short, wh);
      continue;
    }
    j -= NT3;
    if (j < NT4) {
      int jj = (int)(j & 7);
      int lanei = (int)((j >> 3) & 63);
      int nti = (int)((j >> 9) & 3);
      int k32 = (int)((j >> 11) & 63);
      int obi = (int)(j >> 17);
      int o = obi * 64 + nti * 16 + (lanei & 15);
      int k = k32 * 32 + (lanei >> 4) * 8 + jj;
      wfcpack[j] = (short)f2bf(Wfc[(long)o * KFC + k]);
      continue;
    }
    j -= NT4;
    cnt[j] = 0;
  }
}

// ---------------- persistent bidirectional recurrence ----------------
// 128 WGs x 256 thr. WG = (dir, bt 16-row tile, cs 64-col slice); wave = ct.
// Swapped MFMA operands: D[c][b], A = W frags (LDS-stationary 128 KB),
// B = h frags, staged per step as a VERBATIM 32 KB copy xch -> LDS shared
// by all 4 waves (16 u64 sc1 loads/thread -> 8 ds_write_b128).
// Per-wave flags; register-direct coalesced publish; 2 barriers/step.
__global__ __launch_bounds__(256, 1)
void rnn_kernel(const int* __restrict__ xT,
                const float* __restrict__ tableF, const float* __restrict__ tableB,
                const short* __restrict__ whhpack,
                short* __restrict__ hsF, short* __restrict__ hsB,
                short* __restrict__ xch, unsigned int* __restrict__ cnt)
{
  extern __shared__ char lds[];
  char* ldsW = lds;               // 128 KB [ct][kt][lane][16B]
  char* ldsH = lds + 131072;      // 32 KB  [kt][q][lane] u64 (= xch bt-block)
  const int tid = threadIdx.x;
  const int wg = blockIdx.x;
  const int dir = wg >> 6;
  const int bt = (wg >> 4) & 3;
  const int cs = wg & 15;
  const int lane = tid & 63;
  const int ct = tid >> 6;
  const int row = bt * 16 + (lane & 15);            // my batch row
  const int c4 = cs * 64 + ct * 16 + (lane >> 4) * 4;  // my 4 output cols
  const float* table = dir ? tableB : tableF;
  short* hs = dir ? hsB : hsF;
  unsigned int* flags = cnt + (dir * 4 + bt) * 64;  // my class's 64 wave-flags
  unsigned int* myflag = flags + cs * 4 + ct;
  unsigned long long* xch64 = (unsigned long long*)xch;
  const int pub_off = bt * 4096 + (c4 >> 5) * 128 + ((c4 >> 2) & 1) * 64 +
                      (lane & 15) + ((c4 >> 3) & 3) * 16;

  // one-time: W slice (my 64 cols) -> LDS, fragment-linear
  {
    const i32x4* wsrc = (const i32x4*)whhpack + (size_t)(dir * 16 + cs) * 8192;
    i32x4* wdst = (i32x4*)ldsW;
    #pragma unroll
    for (int it = 0; it < 32; ++it)
      wdst[it * 256 + tid] = wsrc[it * 256 + tid];
  }
  __syncthreads();

  const f32x4 zv = {0.f, 0.f, 0.f, 0.f};

  // ---- prologue: step 0 (h_0 = tanh(xw)) ----
  {
    int t0 = dir ? 511 : 0;
    int v = xT[t0 * 64 + row];
    f32x4 xwv = *(const f32x4*)(table + v * 1024 + c4);
    unsigned long long hb = 0, hx = 0;
    #pragma unroll
    for (int r = 0; r < 4; ++r) {
      float e = __expf(2.0f * xwv[r]);
      float h = (e - 1.0f) / (e + 1.0f);
      hb |= (unsigned long long)f2bf(h) << (16 * r);
      union { _Float16 f; unsigned short u; } cv; cv.f = (_Float16)h;
      hx |= (unsigned long long)cv.u << (16 * r);
    }
    *(unsigned long long*)(hs + ((size_t)t0 * 64 + row) * 1024 + c4) = hb;
    __hip_atomic_store(xch64 + ((size_t)(dir * 2) << 14) + pub_off, hx,
                       __ATOMIC_RELAXED, __HIP_MEMORY_SCOPE_AGENT);
    __asm__ __volatile__("s_waitcnt vmcnt(0)" ::: "memory");
    if (lane == 0)
      __hip_atomic_store(myflag, 1u, __ATOMIC_RELAXED, __HIP_MEMORY_SCOPE_AGENT);
  }

  for (int s = 1; s < 512; ++s) {
    const int t = dir ? (511 - s) : s;
    // xw gather early (hides under poll)
    int v = xT[t * 64 + row];
    f32x4 xwv = *(const f32x4*)(table + v * 1024 + c4);

    // poll: all 64 producer-waves of my (dir,bt) class published h_{s-1}
    {
      const unsigned int* fp = flags + lane;
      while (__ballot(__hip_atomic_load(fp, __ATOMIC_RELAXED,
                                        __HIP_MEMORY_SCOPE_AGENT) < (unsigned)s))
        __builtin_amdgcn_s_sleep(1);
    }
    __asm__ __volatile__("" ::: "memory");

    // stage h[16 rows][1024 k] = 32 KB, verbatim copy (coalesced both sides)
    {
      const unsigned long long* sp =
          xch64 + ((size_t)(dir * 2 + ((s - 1) & 1)) << 14) + bt * 4096;
      unsigned long long v0[8], v1[8];
      #pragma unroll
      for (int jj = 0; jj < 8; ++jj) {
        v0[jj] = __hip_atomic_load(sp + jj * 512 + tid * 2,
                                   __ATOMIC_RELAXED, __HIP_MEMORY_SCOPE_AGENT);
        v1[jj] = __hip_atomic_load(sp + jj * 512 + tid * 2 + 1,
                                   __ATOMIC_RELAXED, __HIP_MEMORY_SCOPE_AGENT);
      }
      #pragma unroll
      for (int jj = 0; jj < 8; ++jj) {
        u64x2 w; w[0] = v0[jj]; w[1] = v1[jj];
        *(u64x2*)(ldsH + jj * 4096 + tid * 16) = w;
      }
    }
    __syncthreads();

    // MFMA: D[16 cols ct][16 rows bt] over k=1024
    f32x4 acc4[4] = {zv, zv, zv, zv};
    #pragma unroll
    for (int kt = 0; kt < 32; ++kt) {
      f16x8 af = *(const f16x8*)(ldsW + ((ct * 32 + kt) * 64 + lane) * 16);
      u64x2 bv;
      bv[0] = *(const unsigned long long*)(ldsH + (kt * 128 + lane) * 8);
      bv[1] = *(const unsigned long long*)(ldsH + (kt * 128 + 64 + lane) * 8);
      f16x8 bf = __builtin_bit_cast(f16x8, bv);
      acc4[kt & 3] =
          __builtin_amdgcn_mfma_f32_16x16x32_f16(af, bf, acc4[kt & 3], 0, 0, 0);
    }
    __syncthreads();   // ldsH reads done before next-iter stage

    // epilogue: tanh, hs store, register-direct publish, per-wave flag
    f32x4 accs = (acc4[0] + acc4[1]) + (acc4[2] + acc4[3]);
    unsigned long long hb = 0, hx = 0;
    #pragma unroll
    for (int r = 0; r < 4; ++r) {
      float zz = accs[r] + xwv[r];
      float e = __expf(2.0f * zz);
      float h = (e - 1.0f) / (e + 1.0f);
      hb |= (unsigned long long)f2bf(h) << (16 * r);
      union { _Float16 f; unsigned short u; } cv; cv.f = (_Float16)h;
      hx |= (unsigned long long)cv.u << (16 * r);
    }
    *(unsigned long long*)(hs + ((size_t)t * 64 + row) * 1024 + c4) = hb;
    if (s < 511) {
      __hip_atomic_store(xch64 + ((size_t)(dir * 2 + (s & 1)) << 14) + pub_off,
                         hx, __ATOMIC_RELAXED, __HIP_MEMORY_SCOPE_AGENT);
      __asm__ __volatile__("s_waitcnt vmcnt(0)" ::: "memory");
      if (lane == 0)
        __hip_atomic_store(myflag, (unsigned)(s + 1), __ATOMIC_RELAXED,
                           __HIP_MEMORY_SCOPE_AGENT);
    }
  }
}

// ---------------- FC: out[B*T,1024] = concat(hf,hb) @ Wfc^T + b ----------------
__global__ __launch_bounds__(256, 4)
void fc_kernel(const short* __restrict__ hsF, const short* __restrict__ hsB,
               const short* __restrict__ wfcpack, const float* __restrict__ bfc,
               float* __restrict__ out)
{
  __shared__ short Alds[64 * 64];          // [row][k] swizzled
  __shared__ short Blds[2 * 4 * 64 * 8];   // fragment-linear
  const int tid = threadIdx.x;
  const int lane = tid & 63;
  const int wv = tid >> 6;
  const int mt2 = wv & 1;
  const int nt2 = wv >> 1;
  const int r0 = blockIdx.x * 64;
  const int ob = blockIdx.y;
  const int bb = r0 >> 9;
  const int t0 = r0 & 511;

  f32x4 z = {0.f, 0.f, 0.f, 0.f};
  f32x4 acc[2][2] = {{z, z}, {z, z}};

  for (int kc = 0; kc < KFC / 64; ++kc) {
    {  // stage A tile (64 rows x 64 k)
      int row = tid >> 2;
      int kq = (tid & 3) * 16;
      int k0 = kc * 64;
      const short* hsrc = (k0 < H_) ? hsF : hsB;
      int kk = (k0 < H_) ? k0 : (k0 - H_);
      const short* src = hsrc + ((size_t)(t0 + row) * B_ + bb) * H_ + kk + kq;
      i32x4 v0 = *(const i32x4*)(src);
      i32x4 v1 = *(const i32x4*)(src + 8);
      int sw = (row & 7) << 4;
      *(i32x4*)((char*)Alds + row * 128 + ((kq * 2) ^ sw)) = v0;
      *(i32x4*)((char*)Alds + row * 128 + ((kq * 2 + 16) ^ sw)) = v1;
    }
    {  // stage B tile (fragment-linear, contiguous copy)
      const i32x4* src = (const i32x4*)(wfcpack + ((size_t)ob * 64 + kc * 2) * 2048);
      i32x4* dst = (i32x4*)Blds;
      dst[tid] = src[tid];
      dst[tid + 256] = src[tid + 256];
    }
    __syncthreads();
    #pragma unroll
    for (int k2 = 0; k2 < 2; ++k2) {
      bf16x8 afr[2];
      #pragma unroll
      for (int mi = 0; mi < 2; ++mi) {
        int row = mt2 * 32 + mi * 16 + (lane & 15);
        int off = (k2 * 64 + (lane >> 4) * 16) ^ ((row & 7) << 4);
        afr[mi] = *(const bf16x8*)((const char*)Alds + row * 128 + off);
      }
      #pragma unroll
      for (int ni = 0; ni < 2; ++ni) {
        int ntg = nt2 * 2 + ni;
        bf16x8 bfr = *(const bf16x8*)((const char*)Blds + ((k2 * 4 + ntg) * 64 + lane) * 16);
        #pragma unroll
        for (int mi = 0; mi < 2; ++mi)
          acc[mi][ni] = __builtin_amdgcn_mfma_f32_16x16x32_bf16(afr[mi], bfr, acc[mi][ni], 0, 0, 0);
      }
    }
    __syncthreads();
  }
  #pragma unroll
  for (int mi = 0; mi < 2; ++mi) {
    int row = r0 + mt2 * 32 + mi * 16 + (lane >> 4) * 4;
    #pragma unroll
    for (int ni = 0; ni < 2; ++ni) {
      int o = ob * 64 + nt2 * 32 + ni * 16 + (lane & 15);
      float bias = bfc[o];
      #pragma unroll
      for (int r = 0; r < 4; ++r)
        out[(size_t)(row + r) * O_ + o] = acc[mi][ni][r] + bias;
    }
  }
}

extern "C" void kernel_launch(void* const* d_in, const int* in_sizes, int n_in,
                              void* d_out, int out_size, void* d_ws, size_t ws_size,
                              hipStream_t stream) {
  const int* x = (const int*)d_in[0];
  const float* WihF = (const float*)d_in[1];
  const float* WhhF = (const float*)d_in[2];
  const float* bihF = (const float*)d_in[3];
  const float* bhhF = (const float*)d_in[4];
  const float* WihB = (const float*)d_in[5];
  const float* WhhB = (const float*)d_in[6];
  const float* bihB = (const float*)d_in[7];
  const float* bhhB = (const float*)d_in[8];
  const float* Wfc  = (const float*)d_in[9];
  const float* bfc  = (const float*)d_in[10];
  float* out = (float*)d_out;
  char* ws = (char*)d_ws;

  float* tableF = (float*)(ws + OFF_TABLE_F);
  float* tableB = (float*)(ws + OFF_TABLE_B);
  int* xT = (int*)(ws + OFF_XT);
  short* whhpack = (short*)(ws + OFF_WHH);
  short* wfcpack = (short*)(ws + OFF_WFC);
  short* hsF = (short*)(ws + OFF_HSF);
  short* hsB = (short*)(ws + OFF_HSB);
  short* xch = (short*)(ws + OFF_XCH);
  unsigned int* cnt = (unsigned int*)(ws + OFF_CNT);

  hipFuncSetAttribute((const void*)rnn_kernel,
                      hipFuncAttributeMaxDynamicSharedMemorySize, 163840);

  prep_kernel<<<dim3(2048), dim3(256), 0, stream>>>(
      x, WihF, WhhF, bihF, bhhF, WihB, WhhB, bihB, bhhB, Wfc,
      tableF, tableB, xT, whhpack, wfcpack, cnt);
  rnn_kernel<<<dim3(128), dim3(256), 163840, stream>>>(
      xT, tableF, tableB, whhpack, hsF, hsB, xch, cnt);
  fc_kernel<<<dim3(512, 16), dim3(256), 0, stream>>>(
      hsF, hsB, wfcpack, bfc, out);
}

// Round 8
// 1583.179 us; speedup vs baseline: 3.4255x; 1.2613x over previous
//
#include <hip/hip_runtime.h>
#include <math.h>

#define B_ 64
#define T_ 512
#define H_ 1024
#define V_ 256
#define O_ 1024
#define KFC 2048

typedef short bf16x8 __attribute__((ext_vector_type(8)));
typedef _Float16 f16x8 __attribute__((ext_vector_type(8)));
typedef float f32x4 __attribute__((ext_vector_type(4)));
typedef int   i32x4 __attribute__((ext_vector_type(4)));
typedef unsigned long long u64x2 __attribute__((ext_vector_type(2)));

#define FLIP64 0x8000800080008000ULL

// ---- workspace layout (bytes) ----
#define OFF_TABLE_F 0                 // [V][H] f32 (W_ih^T + b_ih + b_hh), fwd
#define OFF_TABLE_B 1048576           // same, bwd
#define OFF_XT      2097152           // [T][B] i32 (transposed x)
#define OFF_WHH     2228224           // fp16 [d][cs16][ct4][kt32][lane64][8] (4 MB)
#define OFF_WFC     6422528           // fp16 [ob][k32][nt][lane][8] (4 MB)
#define OFF_HSF     10616832          // fp16 frag, sign-flipped: [t][bt][kt][q][lane'] u64 (64 MB)
#define OFF_HSB     77725696          // same, bwd (64 MB)  — adjacent to HSF

// ---------------- prep: tables, transposes, packed weights, hs zeroing ----------------
__global__ void prep_kernel(const int* __restrict__ x,
    const float* __restrict__ WihF, const float* __restrict__ WhhF,
    const float* __restrict__ bihF, const float* __restrict__ bhhF,
    const float* __restrict__ WihB, const float* __restrict__ WhhB,
    const float* __restrict__ bihB, const float* __restrict__ bhhB,
    const float* __restrict__ Wfc,
    float* __restrict__ tableF, float* __restrict__ tableB,
    int* __restrict__ xT, short* __restrict__ whhpack,
    short* __restrict__ wfcpack, unsigned long long* __restrict__ hsz)
{
  const long NT1 = 524288, NT2 = 32768, NT3 = 2097152, NT4 = 2097152;
  const long NT5 = 16777216;  // zero hsF+hsB (adjacent, 128 MB) as u64
  const long total = NT1 + NT2 + NT3 + NT4 + NT5;
  for (long i = (long)blockIdx.x * blockDim.x + threadIdx.x; i < total;
       i += (long)gridDim.x * blockDim.x) {
    long j = i;
    if (j < NT1) {
      int d = (int)(j >> 18);
      int r = (int)(j & 262143);
      int v = r >> 10, h = r & 1023;
      const float* Wih = d ? WihB : WihF;
      const float* bi  = d ? bihB : bihF;
      const float* bh  = d ? bhhB : bhhF;
      (d ? tableB : tableF)[r] = Wih[h * V_ + v] + bi[h] + bh[h];
      continue;
    }
    j -= NT1;
    if (j < NT2) {
      int t = (int)(j >> 6), bb = (int)(j & 63);
      xT[j] = x[bb * T_ + t];
      continue;
    }
    j -= NT2;
    if (j < NT3) {
      // whhpack [d][cs16][ct4][kt32][lane64][8]:
      //   c = cs*64 + ct*16 + (lane&15), k = kt*32 + (lane>>4)*8 + jj
      int d = (int)(j >> 20);
      int r = (int)(j & 1048575);
      int jj = r & 7;
      int lanei = (r >> 3) & 63;
      int kt = (r >> 9) & 31;
      int cti = (r >> 14) & 3;
      int csi = (r >> 16) & 15;
      int c = csi * 64 + cti * 16 + (lanei & 15);
      int k = kt * 32 + (lanei >> 4) * 8 + jj;
      float w = (d ? WhhB : WhhF)[c * H_ + k];
      _Float16 wh = (_Float16)w;
      whhpack[j] = __builtin_bit_cast(short, wh);
      continue;
    }
    j -= NT3;
    if (j < NT4) {
      int jj = (int)(j & 7);
      int lanei = (int)((j >> 3) & 63);
      int nti = (int)((j >> 9) & 3);
      int k32 = (int)((j >> 11) & 63);
      int obi = (int)(j >> 17);
      int o = obi * 64 + nti * 16 + (lanei & 15);
      int k = k32 * 32 + (lanei >> 4) * 8 + jj;
      _Float16 wf = (_Float16)Wfc[(long)o * KFC + k];
      wfcpack[j] = __builtin_bit_cast(short, wf);
      continue;
    }
    j -= NT4;
    hsz[j] = 0ULL;  // unwritten sentinel for the self-signaling exchange
    continue;
  }
}

// ---------------- persistent bidirectional recurrence ----------------
// 128 WGs x 256 thr. WG = (dir, bt 16-row tile, cs 64-col slice); wave = ct.
// Exchange = hs itself: per-step fp16 fragment slots, sign-flip-encoded so a
// written u64 is provably nonzero. Consumer poll IS the data load (16 u64,
// ballot until all nonzero). Producer publish = ONE fire-and-forget sc1 store.
// No flags, no vmcnt drains, no fences. 2 barriers/step (shared LDS staging).
__global__ __launch_bounds__(256, 1)
void rnn_kernel(const int* __restrict__ xT,
                const float* __restrict__ tableF, const float* __restrict__ tableB,
                const short* __restrict__ whhpack,
                unsigned long long* __restrict__ hsfF,
                unsigned long long* __restrict__ hsfB)
{
  extern __shared__ char lds[];
  char* ldsW = lds;               // 128 KB [ct][kt][lane][16B]
  char* ldsH = lds + 131072;      // 32 KB  [kt][q][lane] u64 (decoded h)
  const int tid = threadIdx.x;
  const int wg = blockIdx.x;
  const int dir = wg >> 6;
  const int bt = (wg >> 4) & 3;
  const int cs = wg & 15;
  const int lane = tid & 63;
  const int ct = tid >> 6;
  const int row = bt * 16 + (lane & 15);               // my batch row
  const int c4 = cs * 64 + ct * 16 + (lane >> 4) * 4;  // my 4 output cols
  const float* table = dir ? tableB : tableF;
  unsigned long long* hsx = dir ? hsfB : hsfF;
  const int pub_off = bt * 4096 + (c4 >> 5) * 128 + ((c4 >> 2) & 1) * 64 +
                      (lane & 15) + ((c4 >> 3) & 3) * 16;

  // one-time: W slice (my 64 cols) -> LDS, fragment-linear
  {
    const i32x4* wsrc = (const i32x4*)whhpack + (size_t)(dir * 16 + cs) * 8192;
    i32x4* wdst = (i32x4*)ldsW;
    #pragma unroll
    for (int it = 0; it < 32; ++it)
      wdst[it * 256 + tid] = wsrc[it * 256 + tid];
  }
  __syncthreads();

  const f32x4 zv = {0.f, 0.f, 0.f, 0.f};

  // ---- prologue: step 0 (h_0 = tanh(xw)) ----
  {
    int t0 = dir ? 511 : 0;
    int v = xT[t0 * 64 + row];
    f32x4 xwv = *(const f32x4*)(table + v * 1024 + c4);
    unsigned long long hx = 0;
    #pragma unroll
    for (int r = 0; r < 4; ++r) {
      float e = __expf(2.0f * xwv[r]);
      float h = (e - 1.0f) / (e + 1.0f);
      union { _Float16 f; unsigned short u; } cv; cv.f = (_Float16)h;
      unsigned short u = (cv.u == 0x8000u) ? 0u : cv.u;  // -0 -> +0
      hx |= (unsigned long long)(u ^ 0x8000u) << (16 * r);  // field never 0
    }
    __hip_atomic_store(hsx + (size_t)t0 * 16384 + pub_off, hx,
                       __ATOMIC_RELAXED, __HIP_MEMORY_SCOPE_AGENT);
  }

  for (int s = 1; s < 512; ++s) {
    const int t = dir ? (511 - s) : s;
    const int tprev = dir ? (t + 1) : (t - 1);
    // xw gather early (independent)
    int v = xT[t * 64 + row];
    f32x4 xwv = *(const f32x4*)(table + v * 1024 + c4);

    // poll-load: 16 u64 of h_{s-1}; nonzero == written (self-signaling)
    const unsigned long long* sp =
        hsx + (size_t)tprev * 16384 + bt * 4096 + tid * 2;
    unsigned long long va[8], vb[8];
    for (;;) {
      int miss = 0;
      #pragma unroll
      for (int jj = 0; jj < 8; ++jj) {
        va[jj] = __hip_atomic_load(sp + jj * 512, __ATOMIC_RELAXED,
                                   __HIP_MEMORY_SCOPE_AGENT);
        vb[jj] = __hip_atomic_load(sp + jj * 512 + 1, __ATOMIC_RELAXED,
                                   __HIP_MEMORY_SCOPE_AGENT);
      }
      #pragma unroll
      for (int jj = 0; jj < 8; ++jj)
        miss |= (va[jj] == 0ULL) | (vb[jj] == 0ULL);
      if (!__ballot(miss)) break;
      __builtin_amdgcn_s_sleep(1);
    }
    // decode (un-flip signs) + stage to shared LDS
    #pragma unroll
    for (int jj = 0; jj < 8; ++jj) {
      u64x2 w; w[0] = va[jj] ^ FLIP64; w[1] = vb[jj] ^ FLIP64;
      *(u64x2*)(ldsH + jj * 4096 + tid * 16) = w;
    }
    __syncthreads();

    // MFMA: D[16 cols ct][16 rows bt] over k=1024
    f32x4 acc4[4] = {zv, zv, zv, zv};
    #pragma unroll
    for (int kt = 0; kt < 32; ++kt) {
      f16x8 af = *(const f16x8*)(ldsW + ((ct * 32 + kt) * 64 + lane) * 16);
      u64x2 bv;
      bv[0] = *(const unsigned long long*)(ldsH + (kt * 128 + lane) * 8);
      bv[1] = *(const unsigned long long*)(ldsH + (kt * 128 + 64 + lane) * 8);
      f16x8 bf = __builtin_bit_cast(f16x8, bv);
      acc4[kt & 3] =
          __builtin_amdgcn_mfma_f32_16x16x32_f16(af, bf, acc4[kt & 3], 0, 0, 0);
    }
    __syncthreads();   // ldsH reads done before next-iter stage

    // epilogue: tanh, encode, ONE fire-and-forget publish
    f32x4 accs = (acc4[0] + acc4[1]) + (acc4[2] + acc4[3]);
    unsigned long long hx = 0;
    #pragma unroll
    for (int r = 0; r < 4; ++r) {
      float zz = accs[r] + xwv[r];
      float e = __expf(2.0f * zz);
      float h = (e - 1.0f) / (e + 1.0f);
      union { _Float16 f; unsigned short u; } cv; cv.f = (_Float16)h;
      unsigned short u = (cv.u == 0x8000u) ? 0u : cv.u;
      hx |= (unsigned long long)(u ^ 0x8000u) << (16 * r);
    }
    __hip_atomic_store(hsx + (size_t)t * 16384 + pub_off, hx,
                       __ATOMIC_RELAXED, __HIP_MEMORY_SCOPE_AGENT);
  }
}

// ---------------- FC: out[b*512+t][1024] = concat(hf,hb)@Wfc^T + b (fp16 frag) ----
// t-major blocks: block = (t, ob); A-tile = h[t][all 64 b][64 k] read directly
// from the fragment-layout hs (contiguous 1 KB chunks), XOR-decoded.
__global__ __launch_bounds__(256, 4)
void fc_kernel(const unsigned long long* __restrict__ hsfF,
               const unsigned long long* __restrict__ hsfB,
               const short* __restrict__ wfcpack, const float* __restrict__ bfc,
               float* __restrict__ out)
{
  __shared__ unsigned long long Alds[1024];  // 8 KB [btl*2+ik][128]
  __shared__ short Blds[4096];               // 8 KB fp16 fragment-linear
  const int tid = threadIdx.x;
  const int lane = tid & 63;
  const int wv = tid >> 6;
  const int mt2 = wv & 1;
  const int nt2 = wv >> 1;
  const int t = blockIdx.x;
  const int ob = blockIdx.y;
  const int ik = tid >> 7;            // kt-local (0..1)
  const int btl = (tid >> 5) & 3;     // bt block
  const int w4 = (tid & 31) * 4;      // u64 offset within 128

  const i32x4 flip32 = {(int)0x80008000, (int)0x80008000,
                        (int)0x80008000, (int)0x80008000};
  f32x4 z = {0.f, 0.f, 0.f, 0.f};
  f32x4 acc[2][2] = {{z, z}, {z, z}};

  for (int kc = 0; kc < 32; ++kc) {
    {  // A-stage: 1024 u64 (64 b x 64 k), contiguous 32B per thread
      const unsigned long long* src =
          (kc < 16 ? hsfF : hsfB) + (size_t)t * 16384;
      int kt0 = (kc & 15) * 2;
      const unsigned long long* ap = src + btl * 4096 + (kt0 + ik) * 128 + w4;
      i32x4 a01 = *(const i32x4*)ap ^ flip32;
      i32x4 a23 = *(const i32x4*)(ap + 2) ^ flip32;
      *(i32x4*)&Alds[(btl * 2 + ik) * 128 + w4] = a01;
      *(i32x4*)&Alds[(btl * 2 + ik) * 128 + w4 + 2] = a23;
    }
    {  // B-stage: fragment-linear contiguous copy (2 x k32 blocks)
      const i32x4* src = (const i32x4*)(wfcpack + ((size_t)ob * 64 + kc * 2) * 2048);
      i32x4* dst = (i32x4*)Blds;
      dst[tid] = src[tid];
      dst[tid + 256] = src[tid + 256];
    }
    __syncthreads();
    #pragma unroll
    for (int k2 = 0; k2 < 2; ++k2) {
      f16x8 afr[2];
      #pragma unroll
      for (int mi = 0; mi < 2; ++mi) {
        int btm = mt2 * 2 + mi;
        u64x2 av;
        av[0] = Alds[(btm * 2 + k2) * 128 + lane];
        av[1] = Alds[(btm * 2 + k2) * 128 + 64 + lane];
        afr[mi] = __builtin_bit_cast(f16x8, av);
      }
      #pragma unroll
      for (int ni = 0; ni < 2; ++ni) {
        int ntg = nt2 * 2 + ni;
        f16x8 bfr = *(const f16x8*)((const char*)Blds + ((k2 * 4 + ntg) * 64 + lane) * 16);
        #pragma unroll
        for (int mi = 0; mi < 2; ++mi)
          acc[mi][ni] = __builtin_amdgcn_mfma_f32_16x16x32_f16(afr[mi], bfr, acc[mi][ni], 0, 0, 0);
      }
    }
    __syncthreads();
  }
  #pragma unroll
  for (int mi = 0; mi < 2; ++mi) {
    #pragma unroll
    for (int ni = 0; ni < 2; ++ni) {
      int o = ob * 64 + nt2 * 32 + ni * 16 + (lane & 15);
      float bias = bfc[o];
      #pragma unroll
      for (int r = 0; r < 4; ++r) {
        int b = mt2 * 32 + mi * 16 + (lane >> 4) * 4 + r;
        out[(size_t)(b * 512 + t) * O_ + o] = acc[mi][ni][r] + bias;
      }
    }
  }
}

extern "C" void kernel_launch(void* const* d_in, const int* in_sizes, int n_in,
                              void* d_out, int out_size, void* d_ws, size_t ws_size,
                              hipStream_t stream) {
  const int* x = (const int*)d_in[0];
  const float* WihF = (const float*)d_in[1];
  const float* WhhF = (const float*)d_in[2];
  const float* bihF = (const float*)d_in[3];
  const float* bhhF = (const float*)d_in[4];
  const float* WihB = (const float*)d_in[5];
  const float* WhhB = (const float*)d_in[6];
  const float* bihB = (const float*)d_in[7];
  const float* bhhB = (const float*)d_in[8];
  const float* Wfc  = (const float*)d_in[9];
  const float* bfc  = (const float*)d_in[10];
  float* out = (float*)d_out;
  char* ws = (char*)d_ws;

  float* tableF = (float*)(ws + OFF_TABLE_F);
  float* tableB = (float*)(ws + OFF_TABLE_B);
  int* xT = (int*)(ws + OFF_XT);
  short* whhpack = (short*)(ws + OFF_WHH);
  short* wfcpack = (short*)(ws + OFF_WFC);
  unsigned long long* hsfF = (unsigned long long*)(ws + OFF_HSF);
  unsigned long long* hsfB = (unsigned long long*)(ws + OFF_HSB);

  hipFuncSetAttribute((const void*)rnn_kernel,
                      hipFuncAttributeMaxDynamicSharedMemorySize, 163840);

  prep_kernel<<<dim3(2048), dim3(256), 0, stream>>>(
      x, WihF, WhhF, bihF, bhhF, WihB, WhhB, bihB, bhhB, Wfc,
      tableF, tableB, xT, whhpack, wfcpack, hsfF);
  rnn_kernel<<<dim3(128), dim3(256), 163840, stream>>>(
      xT, tableF, tableB, whhpack, hsfF, hsfB);
  fc_kernel<<<dim3(512, 16), dim3(256), 0, stream>>>(
      hsfF, hsfB, wfcpack, bfc, out);
}